// Round 2
// baseline (1081.840 us; speedup 1.0000x reference)
//
#include <hip/hip_runtime.h>
#include <hip/hip_bf16.h>
#include <stdint.h>

// TransformerConv: S=128, B=16, E=512, H=8, D=64.
// Key algebra: q.kn_ij = (Wknow_h^T q_i).know_ij ;  sum_j aw*kn = Wknow_h.(sum_j aw*know)
// -> never materialize kn (saves 137 GFLOP GEMM + 1.5GB traffic); stream know once.

#define SLEN 128
#define BSZN 16
#define EMBN 512
#define NH 8
#define HD 64
#define MROWS 2048  // SLEN*BSZN

typedef __attribute__((ext_vector_type(8))) short short8;
typedef __attribute__((ext_vector_type(4))) float f32x4;
typedef __attribute__((ext_vector_type(2))) float f32x2;

static __device__ __forceinline__ unsigned short f2bf(float f) {
    union { float f; uint32_t u; } v; v.f = f;
    uint32_t u = v.u;
    return (unsigned short)((u + 0x7FFFu + ((u >> 16) & 1u)) >> 16);
}
static __device__ __forceinline__ float bf2f(unsigned short b) {
    union { uint32_t u; float f; } v; v.u = ((uint32_t)b) << 16; return v.f;
}

// ---------------- K0: convert inputs to bf16 (+ transposed Wknow) ----------------
__global__ __launch_bounds__(256) void convert_kernel(
    const float* __restrict__ x, const float* __restrict__ Wq, const float* __restrict__ Wk,
    const float* __restrict__ Wv, const float* __restrict__ Wskip, const float* __restrict__ Wknow,
    unsigned short* __restrict__ xbf, unsigned short* __restrict__ wcat,
    unsigned short* __restrict__ wknowT, unsigned short* __restrict__ wknow_bf) {
    int t = blockIdx.x * 256 + threadIdx.x;
    if (t < 1048576) {
        xbf[t] = f2bf(x[t]);
    } else if (t < 2097152) {
        int i = t - 1048576;
        const float* w = (i < 262144) ? Wq : (i < 524288) ? Wk : (i < 786432) ? Wv : Wskip;
        wcat[i] = f2bf(w[i & 262143]);
    } else if (t < 2359296) {
        int i = t - 2097152;
        int e = i >> 9, dk = i & 511;
        wknowT[i] = f2bf(Wknow[dk * 512 + e]);   // wknowT[e][dk]
    } else if (t < 2621440) {
        int i = t - 2359296;
        wknow_bf[i] = f2bf(Wknow[i]);
    }
}

// ---------------- K1: proj = x @ [Wq|Wk|Wv|Wskip]^T  (bf16 MFMA, f32 out) ----------------
__global__ __launch_bounds__(256) void gemm_qkvr(
    const unsigned short* __restrict__ A,  // 2048x512 bf16 (x)
    const unsigned short* __restrict__ B,  // 2048x512 bf16 (W rows = n)
    float* __restrict__ C,                 // 2048x2048 f32
    unsigned short* __restrict__ qbf) {    // 2048x512 bf16 copy of q part
    const int tid = threadIdx.x, lane = tid & 63, wid = tid >> 6;
    const int wm = wid >> 1, wn = wid & 1;
    const int m0 = blockIdx.x * 64, n0 = blockIdx.y * 64;
    __shared__ alignas(16) unsigned short Al[64][80];
    __shared__ alignas(16) unsigned short Bl[64][80];
    f32x4 acc[2][2] = {};
    for (int kt = 0; kt < 512; kt += 64) {
        for (int c = tid; c < 512; c += 256) {
            int row = c >> 3, c8 = (c & 7) * 8;
            *(short8*)&Al[row][c8] = *(const short8*)&A[(m0 + row) * 512 + kt + c8];
            *(short8*)&Bl[row][c8] = *(const short8*)&B[(n0 + row) * 512 + kt + c8];
        }
        __syncthreads();
#pragma unroll
        for (int kk = 0; kk < 2; ++kk) {
            int klo = kk * 32 + (lane >> 4) * 8;
            short8 a0 = *(const short8*)&Al[wm * 32 + (lane & 15)][klo];
            short8 a1 = *(const short8*)&Al[wm * 32 + 16 + (lane & 15)][klo];
            short8 b0 = *(const short8*)&Bl[wn * 32 + (lane & 15)][klo];
            short8 b1 = *(const short8*)&Bl[wn * 32 + 16 + (lane & 15)][klo];
            acc[0][0] = __builtin_amdgcn_mfma_f32_16x16x32_bf16(a0, b0, acc[0][0], 0, 0, 0);
            acc[0][1] = __builtin_amdgcn_mfma_f32_16x16x32_bf16(a0, b1, acc[0][1], 0, 0, 0);
            acc[1][0] = __builtin_amdgcn_mfma_f32_16x16x32_bf16(a1, b0, acc[1][0], 0, 0, 0);
            acc[1][1] = __builtin_amdgcn_mfma_f32_16x16x32_bf16(a1, b1, acc[1][1], 0, 0, 0);
        }
        __syncthreads();
    }
#pragma unroll
    for (int s = 0; s < 2; ++s)
#pragma unroll
        for (int t2 = 0; t2 < 2; ++t2)
#pragma unroll
            for (int r = 0; r < 4; ++r) {
                int row = m0 + wm * 32 + s * 16 + (lane >> 4) * 4 + r;
                int col = n0 + wn * 32 + t2 * 16 + (lane & 15);
                float v = acc[s][t2][r];
                C[row * 2048 + col] = v;
                if (col < 512) qbf[row * 512 + col] = f2bf(v);
            }
}

// ---------------- K2: qh[m][h*512+e] = sum_d q[m][h*64+d] * Wknow[h*64+d][e] ----------------
__global__ __launch_bounds__(256) void gemm_qh(
    const unsigned short* __restrict__ qbf,     // 2048x512
    const unsigned short* __restrict__ wknowT,  // 512x512 (e, dk)
    unsigned short* __restrict__ qh) {          // 2048x4096 bf16
    const int tid = threadIdx.x, lane = tid & 63, wid = tid >> 6;
    const int wm = wid >> 1, wn = wid & 1;
    const int m0 = blockIdx.x * 64;
    const int h = blockIdx.y >> 3, e0 = (blockIdx.y & 7) * 64;
    __shared__ alignas(16) unsigned short Al[64][80];
    __shared__ alignas(16) unsigned short Bl[64][80];
    for (int c = tid; c < 512; c += 256) {
        int row = c >> 3, c8 = (c & 7) * 8;
        *(short8*)&Al[row][c8] = *(const short8*)&qbf[(m0 + row) * 512 + h * 64 + c8];
        *(short8*)&Bl[row][c8] = *(const short8*)&wknowT[(e0 + row) * 512 + h * 64 + c8];
    }
    __syncthreads();
    f32x4 acc[2][2] = {};
#pragma unroll
    for (int kk = 0; kk < 2; ++kk) {
        int klo = kk * 32 + (lane >> 4) * 8;
        short8 a0 = *(const short8*)&Al[wm * 32 + (lane & 15)][klo];
        short8 a1 = *(const short8*)&Al[wm * 32 + 16 + (lane & 15)][klo];
        short8 b0 = *(const short8*)&Bl[wn * 32 + (lane & 15)][klo];
        short8 b1 = *(const short8*)&Bl[wn * 32 + 16 + (lane & 15)][klo];
        acc[0][0] = __builtin_amdgcn_mfma_f32_16x16x32_bf16(a0, b0, acc[0][0], 0, 0, 0);
        acc[0][1] = __builtin_amdgcn_mfma_f32_16x16x32_bf16(a0, b1, acc[0][1], 0, 0, 0);
        acc[1][0] = __builtin_amdgcn_mfma_f32_16x16x32_bf16(a1, b0, acc[1][0], 0, 0, 0);
        acc[1][1] = __builtin_amdgcn_mfma_f32_16x16x32_bf16(a1, b1, acc[1][1], 0, 0, 0);
    }
#pragma unroll
    for (int s = 0; s < 2; ++s)
#pragma unroll
        for (int t2 = 0; t2 < 2; ++t2)
#pragma unroll
            for (int r = 0; r < 4; ++r) {
                int row = m0 + wm * 32 + s * 16 + (lane >> 4) * 4 + r;
                int col = wn * 32 + t2 * 16 + (lane & 15);
                qh[(size_t)row * 4096 + h * 512 + e0 + col] = f2bf(acc[s][t2][r]);
            }
}

// ---------------- K3: streaming attention over know (one block per (b,i)) ----------------
__global__ __launch_bounds__(256) void attn_kernel(
    const float* __restrict__ proj,          // 2048x2048 (q|k|v|r)
    const unsigned short* __restrict__ qh,   // 2048x4096 bf16
    const float* __restrict__ know,          // (16,16384,512)
    const int* __restrict__ mask,            // (128,128,128)
    unsigned short* __restrict__ ubf,        // 2048x4096 bf16 out (unnormalized)
    float* __restrict__ uvws,                // 2048x512 f32 out (unnormalized)
    float* __restrict__ denomws) {           // 2048x8
    const int blk = blockIdx.x;
    const int b = blk >> 7, i = blk & 127;
    const int m = i * 16 + b;
    const int tid = threadIdx.x, lane = tid & 63, w = tid >> 6;

    __shared__ alignas(16) float q_lds[512];
    __shared__ float sqk[1024];    // [h*128+j] unscaled q.k
    __shared__ float fmask[1024];  // [h*128+j] 0/1
    __shared__ alignas(16) float u_lds[8 * 512];
    __shared__ float uv_lds[512];
    __shared__ float denom[8];

    for (int t = tid; t < 512; t += 256) q_lds[t] = proj[m * 2048 + t];
    for (int t = tid; t < 1024; t += 256) {
        int h = t >> 7, j = t & 127;
        fmask[t] = (mask[((b * 8 + h) * 128 + i) * 128 + j] != 0) ? 1.0f : 0.0f;
    }
    for (int t = tid; t < 4096; t += 256) u_lds[t] = 0.0f;
    for (int t = tid; t < 512; t += 256) uv_lds[t] = 0.0f;
    if (tid < 8) denom[tid] = 0.0f;

    // qh for this row: lane owns e in [8*lane, 8*lane+8), all 8 heads (64 regs)
    float qhr[8][8];
#pragma unroll
    for (int h = 0; h < 8; ++h) {
        short8 v = *(const short8*)&qh[(size_t)m * 4096 + h * 512 + lane * 8];
#pragma unroll
        for (int e = 0; e < 8; ++e) qhr[h][e] = bf2f((unsigned short)v[e]);
    }
    __syncthreads();

    // phase B: sqk[h][j] = q_h . k_hj (f32, k from L2-resident proj)
    for (int r = 0; r < 4; ++r) {
        int p = tid + r * 256;
        int h = p >> 7, j = p & 127;
        const float* krow = &proj[(j * 16 + b) * 2048 + 512 + h * 64];
        const float* qrow = &q_lds[h * 64];
        float acc = 0.0f;
#pragma unroll
        for (int d4 = 0; d4 < 16; ++d4) {
            f32x4 kv = *(const f32x4*)&krow[d4 * 4];
            f32x4 qv = *(const f32x4*)&qrow[d4 * 4];
            acc += qv[0] * kv[0] + qv[1] * kv[1] + qv[2] * kv[2] + qv[3] * kv[3];
        }
        sqk[p] = acc;
    }
    __syncthreads();

    // main streaming loop: each wave handles j = w, w+4, ..., 32 rows
    const float* knowbase = &know[((size_t)b * 16384 + (size_t)i * 128) * 512];
    float ur[8][8], uvr[8], dreg[8];
#pragma unroll
    for (int h = 0; h < 8; ++h) {
        dreg[h] = 0.0f; uvr[h] = 0.0f;
#pragma unroll
        for (int e = 0; e < 8; ++e) ur[h][e] = 0.0f;
    }
    const int hv = lane >> 3, dblk = lane & 7;
    for (int jj = 0; jj < 32; ++jj) {
        int j = w + jj * 4;
        f32x4 k0 = *(const f32x4*)&knowbase[(size_t)j * 512 + lane * 8];
        f32x4 k1 = *(const f32x4*)&knowbase[(size_t)j * 512 + lane * 8 + 4];
        const float* vrow = &proj[(j * 16 + b) * 2048 + 1024];
        f32x4 v0 = *(const f32x4*)&vrow[hv * 64 + dblk * 8];
        f32x4 v1 = *(const f32x4*)&vrow[hv * 64 + dblk * 8 + 4];
        float ps[8];
#pragma unroll
        for (int h = 0; h < 8; ++h) {
            ps[h] = qhr[h][0] * k0[0] + qhr[h][1] * k0[1] + qhr[h][2] * k0[2] + qhr[h][3] * k0[3]
                  + qhr[h][4] * k1[0] + qhr[h][5] * k1[1] + qhr[h][6] * k1[2] + qhr[h][7] * k1[3];
        }
#pragma unroll
        for (int h = 0; h < 8; ++h) {
#pragma unroll
            for (int off = 32; off > 0; off >>= 1) ps[h] += __shfl_xor(ps[h], off, 64);
        }
        float p[8];
#pragma unroll
        for (int h = 0; h < 8; ++h) {
            float s = (ps[h] + sqk[h * 128 + j]) * 0.125f;
            p[h] = fmask[h * 128 + j] * __expf(s);   // unnormalized; masked -> exact 0
            dreg[h] += p[h];
        }
#pragma unroll
        for (int h = 0; h < 8; ++h) {
            ur[h][0] += p[h] * k0[0]; ur[h][1] += p[h] * k0[1];
            ur[h][2] += p[h] * k0[2]; ur[h][3] += p[h] * k0[3];
            ur[h][4] += p[h] * k1[0]; ur[h][5] += p[h] * k1[1];
            ur[h][6] += p[h] * k1[2]; ur[h][7] += p[h] * k1[3];
        }
        float pv = hv == 0 ? p[0] : hv == 1 ? p[1] : hv == 2 ? p[2] : hv == 3 ? p[3]
                 : hv == 4 ? p[4] : hv == 5 ? p[5] : hv == 6 ? p[6] : p[7];
        uvr[0] += pv * v0[0]; uvr[1] += pv * v0[1]; uvr[2] += pv * v0[2]; uvr[3] += pv * v0[3];
        uvr[4] += pv * v1[0]; uvr[5] += pv * v1[1]; uvr[6] += pv * v1[2]; uvr[7] += pv * v1[3];
    }
    // cross-wave combine via LDS atomics
#pragma unroll
    for (int h = 0; h < 8; ++h)
#pragma unroll
        for (int e = 0; e < 8; ++e) atomicAdd(&u_lds[h * 512 + lane * 8 + e], ur[h][e]);
#pragma unroll
    for (int e = 0; e < 8; ++e) atomicAdd(&uv_lds[hv * 64 + dblk * 8 + e], uvr[e]);
    if (lane == 0) {
#pragma unroll
        for (int h = 0; h < 8; ++h) atomicAdd(&denom[h], dreg[h]);
    }
    __syncthreads();

    for (int t = tid; t < 4096; t += 256) ubf[(size_t)m * 4096 + t] = f2bf(u_lds[t]);
    for (int t = tid; t < 512; t += 256) uvws[m * 512 + t] = uv_lds[t];
    if (tid < 8) denomws[m * 8 + tid] = denom[tid];
}

// ---------------- K4: ak[m][h*64+d] = sum_e u[m][h*512+e] * Wknow[h*64+d][e] ----------------
__global__ __launch_bounds__(256) void gemm_ak(
    const unsigned short* __restrict__ ubf,       // 2048x4096 bf16
    const unsigned short* __restrict__ wknow_bf,  // 512x512 bf16 (row-major)
    float* __restrict__ ak) {                     // 2048x512 f32
    const int tid = threadIdx.x, lane = tid & 63, wid = tid >> 6;
    const int wm = wid >> 1, wn = wid & 1;
    const int m0 = blockIdx.x * 64;
    const int h = blockIdx.y;
    __shared__ alignas(16) unsigned short Al[64][80];
    __shared__ alignas(16) unsigned short Bl[64][80];
    f32x4 acc[2][2] = {};
    for (int kt = 0; kt < 512; kt += 64) {
        for (int c = tid; c < 512; c += 256) {
            int row = c >> 3, c8 = (c & 7) * 8;
            *(short8*)&Al[row][c8] = *(const short8*)&ubf[(size_t)(m0 + row) * 4096 + h * 512 + kt + c8];
            *(short8*)&Bl[row][c8] = *(const short8*)&wknow_bf[(h * 64 + row) * 512 + kt + c8];
        }
        __syncthreads();
#pragma unroll
        for (int kk = 0; kk < 2; ++kk) {
            int klo = kk * 32 + (lane >> 4) * 8;
            short8 a0 = *(const short8*)&Al[wm * 32 + (lane & 15)][klo];
            short8 a1 = *(const short8*)&Al[wm * 32 + 16 + (lane & 15)][klo];
            short8 b0 = *(const short8*)&Bl[wn * 32 + (lane & 15)][klo];
            short8 b1 = *(const short8*)&Bl[wn * 32 + 16 + (lane & 15)][klo];
            acc[0][0] = __builtin_amdgcn_mfma_f32_16x16x32_bf16(a0, b0, acc[0][0], 0, 0, 0);
            acc[0][1] = __builtin_amdgcn_mfma_f32_16x16x32_bf16(a0, b1, acc[0][1], 0, 0, 0);
            acc[1][0] = __builtin_amdgcn_mfma_f32_16x16x32_bf16(a1, b0, acc[1][0], 0, 0, 0);
            acc[1][1] = __builtin_amdgcn_mfma_f32_16x16x32_bf16(a1, b1, acc[1][1], 0, 0, 0);
        }
        __syncthreads();
    }
#pragma unroll
    for (int s = 0; s < 2; ++s)
#pragma unroll
        for (int t2 = 0; t2 < 2; ++t2)
#pragma unroll
            for (int r = 0; r < 4; ++r) {
                int row = m0 + wm * 32 + s * 16 + (lane >> 4) * 4 + r;
                int col = wn * 32 + t2 * 16 + (lane & 15);
                ak[row * 512 + h * 64 + col] = acc[s][t2][r];
            }
}

// ---------------- K5: normalize, gate, output ----------------
__global__ __launch_bounds__(256) void final_kernel(
    const float* __restrict__ uv, const float* __restrict__ ak,
    const float* __restrict__ denomws, const float* __restrict__ proj,
    const float* __restrict__ Wbeta, float* __restrict__ out) {
    const int m = blockIdx.x;
    const int tid = threadIdx.x, lane = tid & 63, w = tid >> 6;
    __shared__ float red[4];
    const int e = tid * 2;
    float den = denomws[m * 8 + (tid >> 5)];
    float a0 = (uv[m * 512 + e] + ak[m * 512 + e]) / den;
    float a1 = (uv[m * 512 + e + 1] + ak[m * 512 + e + 1]) / den;
    f32x2 rv = *(const f32x2*)&proj[m * 2048 + 1536 + e];
    float r0 = rv[0], r1 = rv[1];
    float part = a0 * Wbeta[e] + a1 * Wbeta[e + 1]
               + r0 * Wbeta[512 + e] + r1 * Wbeta[513 + e]
               + (a0 - r0) * Wbeta[1024 + e] + (a1 - r1) * Wbeta[1025 + e];
#pragma unroll
    for (int off = 32; off > 0; off >>= 1) part += __shfl_xor(part, off, 64);
    if (lane == 0) red[w] = part;
    __syncthreads();
    float g = 1.0f / (1.0f + __expf(-(red[0] + red[1] + red[2] + red[3])));
    f32x2 o;
    o[0] = g * r0 + (1.0f - g) * a0;
    o[1] = g * r1 + (1.0f - g) * a1;
    *(f32x2*)&out[m * 512 + e] = o;
}

extern "C" void kernel_launch(void* const* d_in, const int* in_sizes, int n_in,
                              void* d_out, int out_size, void* d_ws, size_t ws_size,
                              hipStream_t stream) {
    const float* x     = (const float*)d_in[0];
    const float* know  = (const float*)d_in[1];
    const int*   mask  = (const int*)d_in[2];
    const float* Wq    = (const float*)d_in[3];
    const float* Wk    = (const float*)d_in[4];
    const float* Wv    = (const float*)d_in[5];
    const float* Wknow = (const float*)d_in[6];
    const float* Wskip = (const float*)d_in[7];
    const float* Wbeta = (const float*)d_in[8];
    float* out = (float*)d_out;
    char* ws = (char*)d_ws;

    // ws layout (bytes). xbf/wcat/wknowT/qbf are dead before ubf is written (aliased inside it).
    float*          proj     = (float*)(ws + 0);               // 16 MB
    unsigned short* qh       = (unsigned short*)(ws + 16777216);   // 16 MB
    unsigned short* ubf      = (unsigned short*)(ws + 33554432);   // 16 MB (written by K3)
    unsigned short* xbf      = (unsigned short*)(ws + 33554432);   // 2 MB  (dead after K1)
    unsigned short* wcat     = (unsigned short*)(ws + 35651584);   // 2 MB  (dead after K1)
    unsigned short* wknowT   = (unsigned short*)(ws + 37748736);   // 512 KB (dead after K2)
    unsigned short* qbf      = (unsigned short*)(ws + 38273024);   // 2 MB  (dead after K2)
    float*          uvws     = (float*)(ws + 50331648);            // 4 MB
    float*          akws     = (float*)(ws + 54525952);            // 4 MB
    float*          denomws  = (float*)(ws + 58720256);            // 64 KB
    unsigned short* wknow_bf = (unsigned short*)(ws + 58785792);   // 512 KB  -> end ~59.3 MB

    convert_kernel<<<10240, 256, 0, stream>>>(x, Wq, Wk, Wv, Wskip, Wknow,
                                              xbf, wcat, wknowT, wknow_bf);
    gemm_qkvr<<<dim3(32, 32), 256, 0, stream>>>(xbf, wcat, proj, qbf);
    gemm_qh<<<dim3(32, 64), 256, 0, stream>>>(qbf, wknowT, qh);
    attn_kernel<<<2048, 256, 0, stream>>>(proj, qh, know, mask, ubf, uvws, denomws);
    gemm_ak<<<dim3(32, 8), 256, 0, stream>>>(ubf, wknow_bf, akws);
    final_kernel<<<2048, 256, 0, stream>>>(uvws, akws, denomws, proj, Wbeta, out);
}

// Round 3
// 828.912 us; speedup vs baseline: 1.3051x; 1.3051x over previous
//
#include <hip/hip_runtime.h>
#include <hip/hip_bf16.h>
#include <stdint.h>

// TransformerConv: S=128, B=16, E=512, H=8, D=64.
// Key algebra: q.kn_ij = (Wknow_h^T q_i).know_ij ;  sum_j aw*kn = Wknow_h.(sum_j aw*know)
// -> never materialize kn. K3 v2: LDS-staged know chunks + MFMA scores + reg-resident u.

#define SLEN 128
#define BSZN 16
#define EMBN 512
#define NH 8
#define HD 64

typedef __attribute__((ext_vector_type(8))) short short8;
typedef __attribute__((ext_vector_type(4))) unsigned short ushort4v;
typedef __attribute__((ext_vector_type(4))) float f32x4;
typedef __attribute__((ext_vector_type(2))) float f32x2;

static __device__ __forceinline__ unsigned short f2bf(float f) {
    union { float f; uint32_t u; } v; v.f = f;
    uint32_t u = v.u;
    return (unsigned short)((u + 0x7FFFu + ((u >> 16) & 1u)) >> 16);
}
static __device__ __forceinline__ float bf2f(unsigned short b) {
    union { uint32_t u; float f; } v; v.u = ((uint32_t)b) << 16; return v.f;
}

// ---------------- K0: convert inputs to bf16 (+ transposed Wknow) ----------------
__global__ __launch_bounds__(256) void convert_kernel(
    const float* __restrict__ x, const float* __restrict__ Wq, const float* __restrict__ Wk,
    const float* __restrict__ Wv, const float* __restrict__ Wskip, const float* __restrict__ Wknow,
    unsigned short* __restrict__ xbf, unsigned short* __restrict__ wcat,
    unsigned short* __restrict__ wknowT, unsigned short* __restrict__ wknow_bf) {
    int t = blockIdx.x * 256 + threadIdx.x;
    if (t < 1048576) {
        xbf[t] = f2bf(x[t]);
    } else if (t < 2097152) {
        int i = t - 1048576;
        const float* w = (i < 262144) ? Wq : (i < 524288) ? Wk : (i < 786432) ? Wv : Wskip;
        wcat[i] = f2bf(w[i & 262143]);
    } else if (t < 2359296) {
        int i = t - 2097152;
        int e = i >> 9, dk = i & 511;
        wknowT[i] = f2bf(Wknow[dk * 512 + e]);   // wknowT[e][dk]
    } else if (t < 2621440) {
        int i = t - 2359296;
        wknow_bf[i] = f2bf(Wknow[i]);
    }
}

// ---------------- K1: proj = x @ [Wq|Wk|Wv|Wskip]^T  (bf16 MFMA, f32 out) ----------------
__global__ __launch_bounds__(256) void gemm_qkvr(
    const unsigned short* __restrict__ A,  // 2048x512 bf16 (x)
    const unsigned short* __restrict__ B,  // 2048x512 bf16 (W rows = n)
    float* __restrict__ C,                 // 2048x2048 f32
    unsigned short* __restrict__ qbf) {    // 2048x512 bf16 copy of q part
    const int tid = threadIdx.x, lane = tid & 63, wid = tid >> 6;
    const int wm = wid >> 1, wn = wid & 1;
    const int m0 = blockIdx.x * 64, n0 = blockIdx.y * 64;
    __shared__ alignas(16) unsigned short Al[64][80];
    __shared__ alignas(16) unsigned short Bl[64][80];
    f32x4 acc[2][2] = {};
    for (int kt = 0; kt < 512; kt += 64) {
        for (int c = tid; c < 512; c += 256) {
            int row = c >> 3, c8 = (c & 7) * 8;
            *(short8*)&Al[row][c8] = *(const short8*)&A[(m0 + row) * 512 + kt + c8];
            *(short8*)&Bl[row][c8] = *(const short8*)&B[(n0 + row) * 512 + kt + c8];
        }
        __syncthreads();
#pragma unroll
        for (int kk = 0; kk < 2; ++kk) {
            int klo = kk * 32 + (lane >> 4) * 8;
            short8 a0 = *(const short8*)&Al[wm * 32 + (lane & 15)][klo];
            short8 a1 = *(const short8*)&Al[wm * 32 + 16 + (lane & 15)][klo];
            short8 b0 = *(const short8*)&Bl[wn * 32 + (lane & 15)][klo];
            short8 b1 = *(const short8*)&Bl[wn * 32 + 16 + (lane & 15)][klo];
            acc[0][0] = __builtin_amdgcn_mfma_f32_16x16x32_bf16(a0, b0, acc[0][0], 0, 0, 0);
            acc[0][1] = __builtin_amdgcn_mfma_f32_16x16x32_bf16(a0, b1, acc[0][1], 0, 0, 0);
            acc[1][0] = __builtin_amdgcn_mfma_f32_16x16x32_bf16(a1, b0, acc[1][0], 0, 0, 0);
            acc[1][1] = __builtin_amdgcn_mfma_f32_16x16x32_bf16(a1, b1, acc[1][1], 0, 0, 0);
        }
        __syncthreads();
    }
#pragma unroll
    for (int s = 0; s < 2; ++s)
#pragma unroll
        for (int t2 = 0; t2 < 2; ++t2)
#pragma unroll
            for (int r = 0; r < 4; ++r) {
                int row = m0 + wm * 32 + s * 16 + (lane >> 4) * 4 + r;
                int col = n0 + wn * 32 + t2 * 16 + (lane & 15);
                float v = acc[s][t2][r];
                C[row * 2048 + col] = v;
                if (col < 512) qbf[row * 512 + col] = f2bf(v);
            }
}

// ---------------- K2: qh[m][h*512+e] = sum_d q[m][h*64+d] * Wknow[h*64+d][e] ----------------
__global__ __launch_bounds__(256) void gemm_qh(
    const unsigned short* __restrict__ qbf,     // 2048x512
    const unsigned short* __restrict__ wknowT,  // 512x512 (e, dk)
    unsigned short* __restrict__ qh) {          // 2048x4096 bf16
    const int tid = threadIdx.x, lane = tid & 63, wid = tid >> 6;
    const int wm = wid >> 1, wn = wid & 1;
    const int m0 = blockIdx.x * 64;
    const int h = blockIdx.y >> 3, e0 = (blockIdx.y & 7) * 64;
    __shared__ alignas(16) unsigned short Al[64][80];
    __shared__ alignas(16) unsigned short Bl[64][80];
    for (int c = tid; c < 512; c += 256) {
        int row = c >> 3, c8 = (c & 7) * 8;
        *(short8*)&Al[row][c8] = *(const short8*)&qbf[(m0 + row) * 512 + h * 64 + c8];
        *(short8*)&Bl[row][c8] = *(const short8*)&wknowT[(e0 + row) * 512 + h * 64 + c8];
    }
    __syncthreads();
    f32x4 acc[2][2] = {};
#pragma unroll
    for (int kk = 0; kk < 2; ++kk) {
        int klo = kk * 32 + (lane >> 4) * 8;
        short8 a0 = *(const short8*)&Al[wm * 32 + (lane & 15)][klo];
        short8 a1 = *(const short8*)&Al[wm * 32 + 16 + (lane & 15)][klo];
        short8 b0 = *(const short8*)&Bl[wn * 32 + (lane & 15)][klo];
        short8 b1 = *(const short8*)&Bl[wn * 32 + 16 + (lane & 15)][klo];
        acc[0][0] = __builtin_amdgcn_mfma_f32_16x16x32_bf16(a0, b0, acc[0][0], 0, 0, 0);
        acc[0][1] = __builtin_amdgcn_mfma_f32_16x16x32_bf16(a0, b1, acc[0][1], 0, 0, 0);
        acc[1][0] = __builtin_amdgcn_mfma_f32_16x16x32_bf16(a1, b0, acc[1][0], 0, 0, 0);
        acc[1][1] = __builtin_amdgcn_mfma_f32_16x16x32_bf16(a1, b1, acc[1][1], 0, 0, 0);
    }
#pragma unroll
    for (int s = 0; s < 2; ++s)
#pragma unroll
        for (int t2 = 0; t2 < 2; ++t2)
#pragma unroll
            for (int r = 0; r < 4; ++r) {
                int row = m0 + wm * 32 + s * 16 + (lane >> 4) * 4 + r;
                int col = wn * 32 + t2 * 16 + (lane & 15);
                qh[(size_t)row * 4096 + h * 512 + e0 + col] = f2bf(acc[s][t2][r]);
            }
}

// ---------------- K3 v2: streaming attention, MFMA scores + reg-resident u ----------------
// block = (b,i). 8 chunks of 16 j-rows. LDS ~39KB -> 4 blocks/CU.
__global__ __launch_bounds__(256, 4) void attn_kernel(
    const float* __restrict__ proj,          // 2048x2048 (q|k|v|r)
    const unsigned short* __restrict__ qh,   // 2048x4096 bf16
    const float* __restrict__ know,          // (16,16384,512)
    const int* __restrict__ mask,            // (128,128,128)
    unsigned short* __restrict__ ubf,        // 2048x4096 bf16 out (unnormalized)
    float* __restrict__ uvws,                // 2048x512 f32 out (unnormalized)
    float* __restrict__ denomws) {           // 2048x8
    const int blk = blockIdx.x;
    const int b = blk >> 7, i = blk & 127;
    const int m = i * 16 + b;
    const int tid = threadIdx.x, lane = tid & 63, w = tid >> 6;

    __shared__ alignas(16) unsigned short know_lds[16][520];  // chunk, bf16, padded
    __shared__ alignas(16) unsigned short qh_lds[16][520];    // rows 8..15 garbage (unused h)
    __shared__ float sqkm[8][128];   // masked q.k (unscaled); masked -> -1e31
    __shared__ float sacc[16][16];   // MFMA score accumulator (rows 8..15 unused)
    __shared__ float p_lds[16][8];   // p[j][h]
    __shared__ float denom[8];

    // ---- qh staging: thread t -> h=t>>5 (8 rows), 32B chunk c=t&31
    {
        int h = tid >> 5, c = tid & 31;
        const unsigned short* src = &qh[(size_t)m * 4096 + h * 512 + c * 16];
        short8 v0 = *(const short8*)src;
        short8 v1 = *(const short8*)(src + 8);
        *(short8*)&qh_lds[h][c * 16] = v0;
        *(short8*)&qh_lds[h][c * 16 + 8] = v1;
    }
    if (tid < 8) denom[tid] = 0.0f;

    // ---- sqkm: 1024 dots of length 64 over proj (L2-resident), mask baked in
    for (int r = 0; r < 4; ++r) {
        int p = tid + r * 256;
        int h = p >> 7, j = p & 127;
        const float* qrow = &proj[m * 2048 + h * 64];
        const float* krow = &proj[(j * 16 + b) * 2048 + 512 + h * 64];
        float acc = 0.0f;
#pragma unroll
        for (int d4 = 0; d4 < 16; ++d4) {
            f32x4 qv = *(const f32x4*)&qrow[d4 * 4];
            f32x4 kv = *(const f32x4*)&krow[d4 * 4];
            acc += qv[0] * kv[0] + qv[1] * kv[1] + qv[2] * kv[2] + qv[3] * kv[3];
        }
        int mk = mask[((b * 8 + h) * 128 + i) * 128 + j];
        sqkm[h][j] = mk ? acc : -1e31f;
    }
    __syncthreads();

    float u[8][2];
#pragma unroll
    for (int h = 0; h < 8; ++h) { u[h][0] = 0.0f; u[h][1] = 0.0f; }
    float uva = 0.0f, uvb = 0.0f;
    const int huv = tid >> 5;          // h for uv-phase (hd = 2*tid, h = hd>>6)
    const size_t knowbase = ((size_t)b * 16384 + (size_t)i * 128) * 512;

    for (int c = 0; c < 8; ++c) {
        // ---- stage know chunk (16 rows x 512 e) as bf16 into LDS
        {
            int jrow = tid >> 4, es = tid & 15;
            const float* src = &know[knowbase + (size_t)(c * 16 + jrow) * 512 + es * 4];
            f32x4 ld[8];
#pragma unroll
            for (int t2 = 0; t2 < 8; ++t2) ld[t2] = *(const f32x4*)(src + t2 * 64);
            if (tid < 128) sacc[tid >> 4][tid & 15] = sqkm[tid >> 4][c * 16 + (tid & 15)];
#pragma unroll
            for (int t2 = 0; t2 < 8; ++t2) {
                ushort4v wv;
                wv[0] = f2bf(ld[t2][0]); wv[1] = f2bf(ld[t2][1]);
                wv[2] = f2bf(ld[t2][2]); wv[3] = f2bf(ld[t2][3]);
                *(ushort4v*)((char*)&know_lds[jrow][0] + es * 8 + t2 * 128) = wv;
            }
        }
        __syncthreads();

        // ---- MFMA: S[16h][16j] += qh16 @ know_chunk^T, K-split 128 per wave
        {
            f32x4 acc = {};
#pragma unroll
            for (int s = 0; s < 4; ++s) {
                int klo = (w * 4 + s) * 32 + (lane >> 4) * 8;
                short8 a = *(const short8*)&qh_lds[lane & 15][klo];
                short8 bb = *(const short8*)&know_lds[lane & 15][klo];
                acc = __builtin_amdgcn_mfma_f32_16x16x32_bf16(a, bb, acc, 0, 0, 0);
            }
#pragma unroll
            for (int r = 0; r < 4; ++r)
                atomicAdd(&sacc[(lane >> 4) * 4 + r][lane & 15], acc[r]);
        }
        __syncthreads();

        // ---- p-phase: p = exp(s*0.125) (masked entries underflow to 0), denom reduce
        if (tid < 128) {
            int h = tid >> 4, j = tid & 15;
            float pp = __expf(sacc[h][j] * 0.125f);
            p_lds[j][h] = pp;
            float ps = pp;
#pragma unroll
            for (int off = 1; off < 16; off <<= 1) ps += __shfl_xor(ps, off, 64);
            if ((tid & 15) == 0) atomicAdd(&denom[h], ps);
        }
        __syncthreads();

        // ---- u-phase (reg accumulate, thread owns e=2*tid..2*tid+1) + uv-phase
        {
            const char* krowbase = (const char*)&know_lds[0][0] + 4 * tid;
#pragma unroll 4
            for (int j = 0; j < 16; ++j) {
                f32x4 p03 = *(const f32x4*)&p_lds[j][0];
                f32x4 p47 = *(const f32x4*)&p_lds[j][4];
                uint32_t kk = *(const uint32_t*)(krowbase + j * 1040);
                float k0 = bf2f((unsigned short)(kk & 0xFFFF));
                float k1 = bf2f((unsigned short)(kk >> 16));
                u[0][0] += p03[0] * k0; u[0][1] += p03[0] * k1;
                u[1][0] += p03[1] * k0; u[1][1] += p03[1] * k1;
                u[2][0] += p03[2] * k0; u[2][1] += p03[2] * k1;
                u[3][0] += p03[3] * k0; u[3][1] += p03[3] * k1;
                u[4][0] += p47[0] * k0; u[4][1] += p47[0] * k1;
                u[5][0] += p47[1] * k0; u[5][1] += p47[1] * k1;
                u[6][0] += p47[2] * k0; u[6][1] += p47[2] * k1;
                u[7][0] += p47[3] * k0; u[7][1] += p47[3] * k1;
                float pv = p_lds[j][huv];
                f32x2 vv = *(const f32x2*)&proj[((c * 16 + j) * 16 + b) * 2048 + 1024 + 2 * tid];
                uva += pv * vv[0]; uvb += pv * vv[1];
            }
        }
        __syncthreads();
    }

    // ---- epilogue: write unnormalized u (bf16), uv (f32), denom
    {
        int e0 = tid * 2;
#pragma unroll
        for (int h = 0; h < 8; ++h) {
            uint32_t pk = (uint32_t)f2bf(u[h][0]) | ((uint32_t)f2bf(u[h][1]) << 16);
            *(uint32_t*)&ubf[(size_t)m * 4096 + h * 512 + e0] = pk;
        }
        f32x2 o; o[0] = uva; o[1] = uvb;
        *(f32x2*)&uvws[m * 512 + e0] = o;
        if (tid < 8) denomws[m * 8 + tid] = denom[tid];
    }
}

// ---------------- K4: ak[m][h*64+d] = sum_e u[m][h*512+e] * Wknow[h*64+d][e] ----------------
__global__ __launch_bounds__(256) void gemm_ak(
    const unsigned short* __restrict__ ubf,       // 2048x4096 bf16
    const unsigned short* __restrict__ wknow_bf,  // 512x512 bf16 (row-major)
    float* __restrict__ ak) {                     // 2048x512 f32
    const int tid = threadIdx.x, lane = tid & 63, wid = tid >> 6;
    const int wm = wid >> 1, wn = wid & 1;
    const int m0 = blockIdx.x * 64;
    const int h = blockIdx.y;
    __shared__ alignas(16) unsigned short Al[64][80];
    __shared__ alignas(16) unsigned short Bl[64][80];
    f32x4 acc[2][2] = {};
    for (int kt = 0; kt < 512; kt += 64) {
        for (int c = tid; c < 512; c += 256) {
            int row = c >> 3, c8 = (c & 7) * 8;
            *(short8*)&Al[row][c8] = *(const short8*)&ubf[(size_t)(m0 + row) * 4096 + h * 512 + kt + c8];
            *(short8*)&Bl[row][c8] = *(const short8*)&wknow_bf[(h * 64 + row) * 512 + kt + c8];
        }
        __syncthreads();
#pragma unroll
        for (int kk = 0; kk < 2; ++kk) {
            int klo = kk * 32 + (lane >> 4) * 8;
            short8 a0 = *(const short8*)&Al[wm * 32 + (lane & 15)][klo];
            short8 a1 = *(const short8*)&Al[wm * 32 + 16 + (lane & 15)][klo];
            short8 b0 = *(const short8*)&Bl[wn * 32 + (lane & 15)][klo];
            short8 b1 = *(const short8*)&Bl[wn * 32 + 16 + (lane & 15)][klo];
            acc[0][0] = __builtin_amdgcn_mfma_f32_16x16x32_bf16(a0, b0, acc[0][0], 0, 0, 0);
            acc[0][1] = __builtin_amdgcn_mfma_f32_16x16x32_bf16(a0, b1, acc[0][1], 0, 0, 0);
            acc[1][0] = __builtin_amdgcn_mfma_f32_16x16x32_bf16(a1, b0, acc[1][0], 0, 0, 0);
            acc[1][1] = __builtin_amdgcn_mfma_f32_16x16x32_bf16(a1, b1, acc[1][1], 0, 0, 0);
        }
        __syncthreads();
    }
#pragma unroll
    for (int s = 0; s < 2; ++s)
#pragma unroll
        for (int t2 = 0; t2 < 2; ++t2)
#pragma unroll
            for (int r = 0; r < 4; ++r) {
                int row = m0 + wm * 32 + s * 16 + (lane >> 4) * 4 + r;
                int col = wn * 32 + t2 * 16 + (lane & 15);
                ak[row * 512 + h * 64 + col] = acc[s][t2][r];
            }
}

// ---------------- K5: normalize, gate, output ----------------
__global__ __launch_bounds__(256) void final_kernel(
    const float* __restrict__ uv, const float* __restrict__ ak,
    const float* __restrict__ denomws, const float* __restrict__ proj,
    const float* __restrict__ Wbeta, float* __restrict__ out) {
    const int m = blockIdx.x;
    const int tid = threadIdx.x, lane = tid & 63, w = tid >> 6;
    __shared__ float red[4];
    const int e = tid * 2;
    float den = denomws[m * 8 + (tid >> 5)];
    float a0 = (uv[m * 512 + e] + ak[m * 512 + e]) / den;
    float a1 = (uv[m * 512 + e + 1] + ak[m * 512 + e + 1]) / den;
    f32x2 rv = *(const f32x2*)&proj[m * 2048 + 1536 + e];
    float r0 = rv[0], r1 = rv[1];
    float part = a0 * Wbeta[e] + a1 * Wbeta[e + 1]
               + r0 * Wbeta[512 + e] + r1 * Wbeta[513 + e]
               + (a0 - r0) * Wbeta[1024 + e] + (a1 - r1) * Wbeta[1025 + e];
#pragma unroll
    for (int off = 32; off > 0; off >>= 1) part += __shfl_xor(part, off, 64);
    if (lane == 0) red[w] = part;
    __syncthreads();
    float g = 1.0f / (1.0f + __expf(-(red[0] + red[1] + red[2] + red[3])));
    f32x2 o;
    o[0] = g * r0 + (1.0f - g) * a0;
    o[1] = g * r1 + (1.0f - g) * a1;
    *(f32x2*)&out[m * 512 + e] = o;
}

extern "C" void kernel_launch(void* const* d_in, const int* in_sizes, int n_in,
                              void* d_out, int out_size, void* d_ws, size_t ws_size,
                              hipStream_t stream) {
    const float* x     = (const float*)d_in[0];
    const float* know  = (const float*)d_in[1];
    const int*   mask  = (const int*)d_in[2];
    const float* Wq    = (const float*)d_in[3];
    const float* Wk    = (const float*)d_in[4];
    const float* Wv    = (const float*)d_in[5];
    const float* Wknow = (const float*)d_in[6];
    const float* Wskip = (const float*)d_in[7];
    const float* Wbeta = (const float*)d_in[8];
    float* out = (float*)d_out;
    char* ws = (char*)d_ws;

    // ws layout (bytes). xbf/wcat/wknowT/qbf are dead before ubf is written (aliased inside it).
    float*          proj     = (float*)(ws + 0);               // 16 MB
    unsigned short* qh       = (unsigned short*)(ws + 16777216);   // 16 MB
    unsigned short* ubf      = (unsigned short*)(ws + 33554432);   // 16 MB (written by K3)
    unsigned short* xbf      = (unsigned short*)(ws + 33554432);   // 2 MB  (dead after K1)
    unsigned short* wcat     = (unsigned short*)(ws + 35651584);   // 2 MB  (dead after K1)
    unsigned short* wknowT   = (unsigned short*)(ws + 37748736);   // 512 KB (dead after K2)
    unsigned short* qbf      = (unsigned short*)(ws + 38273024);   // 2 MB  (dead after K2)
    float*          uvws     = (float*)(ws + 50331648);            // 4 MB
    float*          akws     = (float*)(ws + 54525952);            // 4 MB
    float*          denomws  = (float*)(ws + 58720256);            // 64 KB
    unsigned short* wknow_bf = (unsigned short*)(ws + 58785792);   // 512 KB  -> end ~59.3 MB

    convert_kernel<<<10240, 256, 0, stream>>>(x, Wq, Wk, Wv, Wskip, Wknow,
                                              xbf, wcat, wknowT, wknow_bf);
    gemm_qkvr<<<dim3(32, 32), 256, 0, stream>>>(xbf, wcat, proj, qbf);
    gemm_qh<<<dim3(32, 64), 256, 0, stream>>>(qbf, wknowT, qh);
    attn_kernel<<<2048, 256, 0, stream>>>(proj, qh, know, mask, ubf, uvws, denomws);
    gemm_ak<<<dim3(32, 8), 256, 0, stream>>>(ubf, wknow_bf, akws);
    final_kernel<<<2048, 256, 0, stream>>>(uvws, akws, denomws, proj, Wbeta, out);
}